// Round 7
// baseline (272.996 us; speedup 1.0000x reference)
//
#include <hip/hip_runtime.h>

// Problem constants
#define B_ 256
#define T_ 64
#define N_ 128
#define H_ 128
#define G3 384   // 3*H (gate rows)
#define K2 256   // 2*H (packed matvec K range: [agg ; prev])

// Workspace layout (float offsets)
#define WS_G    0                    // G table: 384*384  (b_ih + W_ih[:, :H] @ emb[e])
#define WS_PW   (WS_G + G3*G3)       // packed transposed weights: 256*384
#define WS_NZC  (WS_PW + K2*G3)      // 128 ints: nonzero counts
#define WS_NZP  (WS_NZC + 128)       // 128*128 int2 pairs (n, w bits)

// ---------------------------------------------------------------------------
// Single prep kernel (unchanged): G table, adj nonzero lists, packed weights
// ---------------------------------------------------------------------------
__global__ void __launch_bounds__(384) prep(
        const float* __restrict__ W_ih, const float* __restrict__ W_hh,
        const float* __restrict__ emb,  const float* __restrict__ b_ih,
        const float* __restrict__ adj,  float* __restrict__ ws) {
    const int bid = blockIdx.x;
    if (bid < 384) {
        __shared__ float es[H_];
        const int e = bid, j = threadIdx.x;
        if (j < H_) es[j] = emb[e * H_ + j];
        __syncthreads();
        float acc = b_ih[j];
        const float4* wrow = (const float4*)(W_ih + j * K2);  // row j, cols [0,128)
        #pragma unroll 8
        for (int i = 0; i < 32; ++i) {
            float4 w = wrow[i];
            acc += w.x * es[4*i];
            acc += w.y * es[4*i + 1];
            acc += w.z * es[4*i + 2];
            acc += w.w * es[4*i + 3];
        }
        (ws + WS_G)[e * G3 + j] = acc;
    } else if (bid < 512) {
        __shared__ float row[N_];
        const int r = bid - 384;
        if (threadIdx.x < N_) row[threadIdx.x] = adj[r * N_ + threadIdx.x];
        __syncthreads();
        if (threadIdx.x == 0) {
            int*  nzc = (int*)(ws + WS_NZC);
            int2* nzp = (int2*)(ws + WS_NZP);
            int cnt = 0;
            for (int n = 0; n < N_; ++n) {
                float w = row[n];
                if (w != 0.0f) { nzp[r * N_ + cnt] = make_int2(n, __float_as_int(w)); ++cnt; }
            }
            int cnt4 = (cnt + 3) & ~3;
            for (int i = cnt; i < cnt4; ++i) nzp[r * N_ + i] = make_int2(0, 0); // w=0 pad
            nzc[r] = cnt;
        }
    } else {
        const int k = bid - 512, j = threadIdx.x;
        (ws + WS_PW)[k * G3 + j] = (k < H_) ? W_ih[j * K2 + H_ + k]
                                            : W_hh[j * H_ + (k - H_)];
    }
}

// ---------------------------------------------------------------------------
// Main kernel: one block per batch PAIR (128 blocks, 768 threads = 12 waves).
// Weight traffic halves: each weight read once/step serves BOTH batches.
// Thread (kc = tid/192 in [0,4), j2 = tid%192) streams K-chunk [64kc,64kc+64)
// of rows {j2, j2+192}: 128 coalesced b32 loads, 256 FMAs (2 batches).
// kc 0-1 = agg half (k<128), kc 2-3 = hidden half -> n-gate split by kc.
// Phase A: dual-batch matvec partials -> pl[batch][kc][row]; side jobs:
//   tids 512-767 stage next nz rows (both batches); tids 0-127 finalize
//   prev-step logits (wave 0 = batch0, wave 1 = batch1); tids 0-511
//   prefetch prevreg + G row for phase B.
// Phase B: tids 0-255 gates+h-write+red (bt=tid>>7); tids 256-511 dup gates
//   + agg(s+1) with hnew substitution; tids 512-767 store prev logits rows.
// LDS total = 149,512 B (h 128K + pl 12K + small buffers) -> 1 block/CU.
// ---------------------------------------------------------------------------
__global__ void __launch_bounds__(768, 3) gkt_main(
        const int* __restrict__ task_seq, const int* __restrict__ status_seq,
        const float* __restrict__ b_hh,   const float* __restrict__ w_pred,
        const float* __restrict__ b_pred, const float* __restrict__ ws,
        float* __restrict__ out) {
    __shared__ __align__(16) float h_lds[2][N_ * H_];   // 128 KB state (2 batches)
    __shared__ __align__(16) float aggbuf[2][H_];       // agg vectors
    __shared__ float pl[2][4][G3];                      // matvec partials, 12 KB
    __shared__ float red[2][H_];                        // logit-dot partials
    __shared__ float Ll[2][N_];                         // running logits
    __shared__ int2  nzbuf[2][N_];                      // staged nz lists
    __shared__ int   nz_cnt[2];
    __shared__ int   tasks_l[2][T_], stats_l[2][T_];

    const int b0  = blockIdx.x * 2;
    const int tid = threadIdx.x;
    const int kc  = tid / 192;           // K-chunk [0,4), wave-uniform (192=3 waves)
    const int j2  = tid - kc * 192;      // row id in [0,192)
    const int bt  = (tid >> 7) & 1;      // batch for B-phase roles
    const int tg  = tid & 127;

    const float* G   = ws + WS_G;
    const float* PW  = ws + WS_PW;
    const int*   nzc = (const int*)(ws + WS_NZC);
    const int2*  nzp = (const int2*)(ws + WS_NZP);

    const float bp = b_pred[0];
    float bhr = 0.f, bhz = 0.f, bhn = 0.f, wpt = 0.f;
    if (tid < 512) { bhr = b_hh[tg]; bhz = b_hh[128 + tg]; bhn = b_hh[256 + tg]; }
    if (tid < 256) wpt = w_pred[tg];

    // ---- init
    for (int i = tid; i < 2 * N_ * H_; i += 768) ((float*)h_lds)[i] = 0.0f;
    if (tid < 64)        tasks_l[0][tid]       = task_seq[(size_t)b0 * T_ + tid];
    else if (tid < 128)  tasks_l[1][tid - 64]  = task_seq[(size_t)(b0 + 1) * T_ + (tid - 64)];
    else if (tid < 192)  stats_l[0][tid - 128] = status_seq[(size_t)b0 * T_ + (tid - 128)];
    else if (tid < 256)  stats_l[1][tid - 192] = status_seq[(size_t)(b0 + 1) * T_ + (tid - 192)];
    if (tid >= 256 && tid < 512) {
        const int bb = (tid >> 7) & 1, t = tid & 127;
        Ll[bb][t] = bp;                  // h0=0 -> logits = b_pred
        aggbuf[bb][t] = 0.0f;            // agg for step 0
    }
    __syncthreads();

    #pragma unroll 1
    for (int s = 0; s < T_; ++s) {
        const int task0 = tasks_l[0][s], task1 = tasks_l[1][s];
        const int taskb = bt ? task1 : task0;

        // ---- Phase A ----------------------------------------------------
        float prevreg = 0.f, g0 = 0.f, g1 = 0.f, g2 = 0.f;
        if (tid < 512) {                 // prefetch for phase B
            prevreg = h_lds[bt][taskb * H_ + tg];
            const int e = taskb * 3 + stats_l[bt][s];
            g0 = G[e * G3 + tg];
            g1 = G[e * G3 + 128 + tg];
            g2 = G[e * G3 + 256 + tg];
        }
        {   // dual-batch matvec: 128 weight loads serve 256 FMAs
            const float* wb  = PW + (kc * 64) * G3 + j2;
            const float* vs0 = (kc < 2) ? (&aggbuf[0][kc * 64])
                                        : (&h_lds[0][task0 * H_ + (kc - 2) * 64]);
            const float* vs1 = (kc < 2) ? (&aggbuf[1][kc * 64])
                                        : (&h_lds[1][task1 * H_ + (kc - 2) * 64]);
            float aA0 = 0.f, aB0 = 0.f, aA1 = 0.f, aB1 = 0.f;
            #pragma unroll
            for (int i = 0; i < 16; ++i) {
                const float4 u0 = *(const float4*)(vs0 + 4 * i);   // wave-uniform LDS
                const float4 u1 = *(const float4*)(vs1 + 4 * i);
                const float wa0 = wb[(4*i+0)*G3],       wa1 = wb[(4*i+1)*G3];
                const float wa2 = wb[(4*i+2)*G3],       wa3 = wb[(4*i+3)*G3];
                const float wc0 = wb[(4*i+0)*G3 + 192], wc1 = wb[(4*i+1)*G3 + 192];
                const float wc2 = wb[(4*i+2)*G3 + 192], wc3 = wb[(4*i+3)*G3 + 192];
                aA0 += wa0*u0.x; aA0 += wa1*u0.y; aA0 += wa2*u0.z; aA0 += wa3*u0.w;
                aB0 += wc0*u0.x; aB0 += wc1*u0.y; aB0 += wc2*u0.z; aB0 += wc3*u0.w;
                aA1 += wa0*u1.x; aA1 += wa1*u1.y; aA1 += wa2*u1.z; aA1 += wa3*u1.w;
                aB1 += wc0*u1.x; aB1 += wc1*u1.y; aB1 += wc2*u1.z; aB1 += wc3*u1.w;
            }
            pl[0][kc][j2]       = aA0;
            pl[0][kc][j2 + 192] = aB0;
            pl[1][kc][j2]       = aA1;
            pl[1][kc][j2 + 192] = aB1;
        }
        if (tid >= 512 && s + 1 < T_) {  // stage next nz rows (both batches)
            const int bb = (tid >> 7) & 1, t = tid & 127;
            const int tn = tasks_l[bb][s + 1];
            nzbuf[bb][t] = nzp[tn * N_ + t];
            if (t == 0) nz_cnt[bb] = nzc[tn];
        }
        if (tid < 128 && s > 0) {        // finalize prev-step logits (2 waves)
            const int bb = tid >> 6, lane = tid & 63;
            float x = red[bb][lane] + red[bb][lane + 64];
            #pragma unroll
            for (int off = 32; off > 0; off >>= 1) x += __shfl_xor(x, off, 64);
            if (lane == 0) Ll[bb][tasks_l[bb][s - 1]] = x + bp;
        }
        __syncthreads();

        // ---- Phase B ----------------------------------------------------
        if (tid < 512) {
            float sr  = g0 + bhr + (pl[bt][0][tg] + pl[bt][1][tg])
                                 + (pl[bt][2][tg] + pl[bt][3][tg]);
            float sz  = g1 + bhz + (pl[bt][0][128+tg] + pl[bt][1][128+tg])
                                 + (pl[bt][2][128+tg] + pl[bt][3][128+tg]);
            float in_ = g2 + (pl[bt][0][256+tg] + pl[bt][1][256+tg]);   // i_n (agg half)
            float hn_ = bhn + (pl[bt][2][256+tg] + pl[bt][3][256+tg]);  // h_n (hidden half)
            float r = 1.0f / (1.0f + expf(-sr));
            float z = 1.0f / (1.0f + expf(-sz));
            float n = tanhf(in_ + r * hn_);
            float hnew = (1.0f - z) * n + z * prevreg;
            if (tid < 256) {
                h_lds[bt][taskb * H_ + tg] = hnew;
                red[bt][tg] = hnew * wpt;
            } else if (s + 1 < T_) {     // agg for step s+1 (hnew substitution)
                float acc = 0.0f;
                const int cnt4 = (nz_cnt[bt] + 3) & ~3;
                for (int i = 0; i < cnt4; i += 4) {
                    int2 p0 = nzbuf[bt][i],   p1 = nzbuf[bt][i+1];
                    int2 p2 = nzbuf[bt][i+2], p3 = nzbuf[bt][i+3];
                    float h0 = (p0.x == taskb) ? hnew : h_lds[bt][p0.x * H_ + tg];
                    float h1 = (p1.x == taskb) ? hnew : h_lds[bt][p1.x * H_ + tg];
                    float h2 = (p2.x == taskb) ? hnew : h_lds[bt][p2.x * H_ + tg];
                    float h3 = (p3.x == taskb) ? hnew : h_lds[bt][p3.x * H_ + tg];
                    acc += __int_as_float(p0.y) * h0;
                    acc += __int_as_float(p1.y) * h1;
                    acc += __int_as_float(p2.y) * h2;
                    acc += __int_as_float(p3.y) * h3;
                }
                aggbuf[bt][tg] = acc;
            }
        } else {
            if (s > 0) {
                const int bb = (tid >> 7) & 1, t = tid & 127;
                out[(size_t)(b0 + bb) * T_ * N_ + (size_t)(s - 1) * N_ + t] = Ll[bb][t];
            }
        }
        __syncthreads();
    }

    // ---- epilogue: final logit update, last logits rows, final hidden states
    if (tid < 128) {
        const int bb = tid >> 6, lane = tid & 63;
        float x = red[bb][lane] + red[bb][lane + 64];
        #pragma unroll
        for (int off = 32; off > 0; off >>= 1) x += __shfl_xor(x, off, 64);
        if (lane == 0) Ll[bb][tasks_l[bb][T_ - 1]] = x + bp;
    }
    __syncthreads();
    if (tid < 256) {
        out[(size_t)(b0 + bt) * T_ * N_ + (size_t)(T_ - 1) * N_ + tg] = Ll[bt][tg];
    }
    {
        const size_t hbase = (size_t)B_ * T_ * N_;
        const int qb = N_ * H_ / 4;      // float4s per batch state
        for (int i = tid; i < 2 * qb; i += 768) {
            const int bb = i / qb, r = i - bb * qb;
            ((float4*)(out + hbase + (size_t)(b0 + bb) * N_ * H_))[r] =
                ((const float4*)h_lds[bb])[r];
        }
    }
}

// ---------------------------------------------------------------------------
extern "C" void kernel_launch(void* const* d_in, const int* in_sizes, int n_in,
                              void* d_out, int out_size, void* d_ws, size_t ws_size,
                              hipStream_t stream) {
    const int*   task = (const int*)d_in[0];
    const int*   stat = (const int*)d_in[1];
    const float* adj  = (const float*)d_in[2];
    const float* emb  = (const float*)d_in[3];
    const float* Wih  = (const float*)d_in[4];
    const float* Whh  = (const float*)d_in[5];
    const float* bih  = (const float*)d_in[6];
    const float* bhh  = (const float*)d_in[7];
    const float* wp   = (const float*)d_in[8];
    const float* bp   = (const float*)d_in[9];
    float* out = (float*)d_out;
    float* ws  = (float*)d_ws;

    prep    <<<768, 384, 0, stream>>>(Wih, Whh, emb, bih, adj, ws);
    gkt_main<<<128, 768, 0, stream>>>(task, stat, bhh, wp, bp, ws, out);
}